// Round 1
// baseline (1740.551 us; speedup 1.0000x reference)
//
#include <hip/hip_runtime.h>
#include <hip/hip_bf16.h>
#include <math.h>

#define DIM   384
#define HEADS 8
#define HD    48
#define NTOK  32768   // 8 * 64 * 64
#define NWIN  512     // 8 images * 64 windows

__device__ __forceinline__ float bf2f(unsigned short u) {
    unsigned int v = ((unsigned int)u) << 16;
    return __uint_as_float(v);
}
__device__ __forceinline__ unsigned short f2bf(float f) {
    unsigned int x = __float_as_uint(f);
    unsigned int r = (x + 0x7fffu + ((x >> 16) & 1u)) >> 16;  // RNE
    return (unsigned short)r;
}

// token (window order) -> source pixel of x (accounting for roll by -SHIFT)
__device__ __forceinline__ void tok2src(int tok, int& b, int& hs, int& ws) {
    int bb  = tok >> 12;          // 4096 tokens per image
    int win = (tok >> 6) & 63;
    int t   = tok & 63;
    int hi = win >> 3, wi = win & 7;
    int r  = t >> 3,  cc = t & 7;
    b  = bb;
    hs = (hi * 8 + r  + 4) & 63;
    ws = (wi * 8 + cc + 4) & 63;
}

// ---------------- Kernel 1: gather + LayerNorm1 -> ln1 (bf16, token order) ---
__global__ __launch_bounds__(64) void k_ln1(const float* __restrict__ x,
                                            const float* __restrict__ g,
                                            const float* __restrict__ bt,
                                            unsigned short* __restrict__ ln1) {
    int win = blockIdx.x;
    int t   = threadIdx.x;
    int b  = win >> 6;
    int hi = (win >> 3) & 7;
    int wi = win & 7;
    int r = t >> 3, cc = t & 7;
    int hs = (hi * 8 + r + 4) & 63;
    int wsrc = (wi * 8 + cc + 4) & 63;
    const float* px = x + (size_t)b * DIM * 4096 + hs * 64 + wsrc;

    float sum = 0.f, sq = 0.f;
    for (int c = 0; c < DIM; c++) {
        float v = px[(size_t)c * 4096];
        sum += v; sq += v * v;
    }
    float mean = sum * (1.0f / DIM);
    float var  = sq * (1.0f / DIM) - mean * mean;
    float rstd = rsqrtf(var + 1e-5f);

    __shared__ unsigned short tile[64][DIM + 2];   // +2 pad: conflict-free
    for (int c = 0; c < DIM; c++) {
        float v = (px[(size_t)c * 4096] - mean) * rstd * g[c] + bt[c];
        tile[t][c] = f2bf(v);
    }
    __syncthreads();
    int tok0 = win * 64;
    for (int tk = 0; tk < 64; tk++) {
        #pragma unroll
        for (int i = 0; i < 6; i++) {
            int c = i * 64 + t;
            ln1[(size_t)(tok0 + tk) * DIM + c] = tile[tk][c];
        }
    }
}

// ---------------- Generic tiled GEMM: C[M,N] = A[M,K](bf16) * W[K,N](f32) + bias
// EPI: 0 = bias -> bf16 out; 1 = bias+gelu -> bf16 out;
//      2 = bias + residual gather(x) -> f32 out;  3 = bias -> f32 out
template <int EPI>
__global__ __launch_bounds__(256) void k_gemm(const unsigned short* __restrict__ A,
                                              const float* __restrict__ Wt,
                                              const float* __restrict__ bias,
                                              void* __restrict__ Cout,
                                              const float* __restrict__ xres,
                                              int N, int K) {
    __shared__ float As[16][72];   // [k][m], padded
    __shared__ float Bs[16][64];   // [k][n]
    int tid = threadIdx.x;
    int tx = tid & 15, ty = tid >> 4;
    int m0 = blockIdx.y * 64, n0 = blockIdx.x * 64;

    float acc[4][4] = {};

    int arow = tid >> 2;          // 0..63
    int acol = (tid & 3) * 4;     // 0,4,8,12
    int wrow = tid >> 4;          // 0..15
    int wcol = (tid & 15) * 4;    // 0..60

    for (int k0 = 0; k0 < K; k0 += 16) {
        const unsigned short* ap = A + (size_t)(m0 + arow) * K + k0 + acol;
        ushort4 av = *(const ushort4*)ap;
        As[acol + 0][arow] = bf2f(av.x);
        As[acol + 1][arow] = bf2f(av.y);
        As[acol + 2][arow] = bf2f(av.z);
        As[acol + 3][arow] = bf2f(av.w);
        const float* wp = Wt + (size_t)(k0 + wrow) * N + n0 + wcol;
        *(float4*)&Bs[wrow][wcol] = *(const float4*)wp;
        __syncthreads();
        #pragma unroll
        for (int k = 0; k < 16; k++) {
            float4 a = *(const float4*)&As[k][ty * 4];
            float4 b = *(const float4*)&Bs[k][tx * 4];
            acc[0][0] += a.x * b.x; acc[0][1] += a.x * b.y; acc[0][2] += a.x * b.z; acc[0][3] += a.x * b.w;
            acc[1][0] += a.y * b.x; acc[1][1] += a.y * b.y; acc[1][2] += a.y * b.z; acc[1][3] += a.y * b.w;
            acc[2][0] += a.z * b.x; acc[2][1] += a.z * b.y; acc[2][2] += a.z * b.z; acc[2][3] += a.z * b.w;
            acc[3][0] += a.w * b.x; acc[3][1] += a.w * b.y; acc[3][2] += a.w * b.z; acc[3][3] += a.w * b.w;
        }
        __syncthreads();
    }

    #pragma unroll
    for (int i = 0; i < 4; i++) {
        int m = m0 + ty * 4 + i;
        #pragma unroll
        for (int j = 0; j < 4; j++) {
            int n = n0 + tx * 4 + j;
            float v = acc[i][j] + bias[n];
            if (EPI == 0) {
                ((unsigned short*)Cout)[(size_t)m * N + n] = f2bf(v);
            } else if (EPI == 1) {
                v = 0.5f * v * (1.0f + erff(v * 0.70710678118654752f));
                ((unsigned short*)Cout)[(size_t)m * N + n] = f2bf(v);
            } else if (EPI == 2) {
                int b, hs, ws_;
                tok2src(m, b, hs, ws_);
                v += xres[(((size_t)b * DIM + n) * 64 + hs) * 64 + ws_];
                ((float*)Cout)[(size_t)m * N + n] = v;
            } else {
                ((float*)Cout)[(size_t)m * N + n] = v;
            }
        }
    }
}

// ---------------- Kernel 3: attention per (window, head) ------------------
__global__ __launch_bounds__(64) void k_attn(const unsigned short* __restrict__ qkv,
                                             unsigned short* __restrict__ attn) {
    int win  = blockIdx.x >> 3;
    int head = blockIdx.x & 7;
    int t    = threadIdx.x;
    int tok0 = win * 64;

    __shared__ float Ks[64][52];   // padded to 16B-aligned rows
    __shared__ float Vs[64][52];

    const unsigned short* rowp = qkv + (size_t)(tok0 + t) * (3 * DIM);
    #pragma unroll
    for (int d = 0; d < HD; d++) {
        Ks[t][d] = bf2f(rowp[DIM + head * HD + d]);
        Vs[t][d] = bf2f(rowp[2 * DIM + head * HD + d]);
    }
    const float scale = 0.14433756729740643f;  // 48^-0.5
    float q[HD];
    #pragma unroll
    for (int d = 0; d < HD; d++) q[d] = bf2f(rowp[head * HD + d]) * scale;
    __syncthreads();

    float s[64];
    float mx = -1e30f;
    #pragma unroll
    for (int m = 0; m < 64; m++) {
        float acc = 0.f;
        #pragma unroll
        for (int d4 = 0; d4 < HD / 4; d4++) {
            float4 kk = *(const float4*)&Ks[m][d4 * 4];
            acc += q[d4 * 4 + 0] * kk.x + q[d4 * 4 + 1] * kk.y
                 + q[d4 * 4 + 2] * kk.z + q[d4 * 4 + 3] * kk.w;
        }
        s[m] = acc;
        mx = fmaxf(mx, acc);
    }
    float denom = 0.f;
    #pragma unroll
    for (int m = 0; m < 64; m++) {
        float e = __expf(s[m] - mx);
        s[m] = e;
        denom += e;
    }
    float inv = 1.0f / denom;
    float out[HD];
    #pragma unroll
    for (int d = 0; d < HD; d++) out[d] = 0.f;
    #pragma unroll
    for (int m = 0; m < 64; m++) {
        float p = s[m] * inv;
        #pragma unroll
        for (int d4 = 0; d4 < HD / 4; d4++) {
            float4 vv = *(const float4*)&Vs[m][d4 * 4];
            out[d4 * 4 + 0] += p * vv.x;
            out[d4 * 4 + 1] += p * vv.y;
            out[d4 * 4 + 2] += p * vv.z;
            out[d4 * 4 + 3] += p * vv.w;
        }
    }
    unsigned short* op = attn + (size_t)(tok0 + t) * DIM + head * HD;
    #pragma unroll
    for (int d = 0; d < HD; d++) op[d] = f2bf(out[d]);
}

// ---------------- Kernel 5: LayerNorm2 over y (f32) -> ln2 (bf16) ----------
__global__ __launch_bounds__(64) void k_ln2(const float* __restrict__ y,
                                            const float* __restrict__ g,
                                            const float* __restrict__ bt,
                                            unsigned short* __restrict__ out) {
    int tok = blockIdx.x;
    int t   = threadIdx.x;
    const float* row = y + (size_t)tok * DIM;
    float v[6];
    float sum = 0.f, sq = 0.f;
    #pragma unroll
    for (int i = 0; i < 6; i++) {
        v[i] = row[i * 64 + t];
        sum += v[i]; sq += v[i] * v[i];
    }
    #pragma unroll
    for (int o = 32; o > 0; o >>= 1) {
        sum += __shfl_xor(sum, o, 64);
        sq  += __shfl_xor(sq, o, 64);
    }
    float mean = sum * (1.0f / DIM);
    float var  = sq * (1.0f / DIM) - mean * mean;
    float rstd = rsqrtf(var + 1e-5f);
    unsigned short* orow = out + (size_t)tok * DIM;
    #pragma unroll
    for (int i = 0; i < 6; i++) {
        int c = i * 64 + t;
        orow[c] = f2bf((v[i] - mean) * rstd * g[c] + bt[c]);
    }
}

// ---------------- Kernel 8: un-permute + transpose to [B,C,H,W] ------------
__global__ __launch_bounds__(256) void k_out(const float* __restrict__ hbuf,
                                             float* __restrict__ out) {
    int bh = blockIdx.x;
    int b = bh >> 6, h = bh & 63;
    int t = threadIdx.x;
    __shared__ float T[64][193];
    int hh = (h + 60) & 63;
    int hi = hh >> 3, r = hh & 7;
    for (int half = 0; half < 2; half++) {
        int c0 = half * 192;
        for (int idx = t; idx < 64 * 192; idx += 256) {
            int w = idx / 192;
            int c = idx - w * 192;
            int ww = (w + 60) & 63;
            int wi = ww >> 3, cc2 = ww & 7;
            int tok = ((b * 8 + hi) * 8 + wi) * 64 + r * 8 + cc2;
            T[w][c] = hbuf[(size_t)tok * DIM + c0 + c];
        }
        __syncthreads();
        for (int idx = t; idx < 64 * 192; idx += 256) {
            int cc = idx >> 6;
            int w  = idx & 63;
            out[(((size_t)b * DIM + c0 + cc) * 64 + h) * 64 + w] = T[w][cc];
        }
        __syncthreads();
    }
}

extern "C" void kernel_launch(void* const* d_in, const int* in_sizes, int n_in,
                              void* d_out, int out_size, void* d_ws, size_t ws_size,
                              hipStream_t stream) {
    const float* x      = (const float*)d_in[0];
    const float* qkv_w  = (const float*)d_in[1];
    const float* qkv_b  = (const float*)d_in[2];
    const float* proj_w = (const float*)d_in[3];
    const float* proj_b = (const float*)d_in[4];
    const float* ln1_g  = (const float*)d_in[5];
    const float* ln1_b  = (const float*)d_in[6];
    const float* ln2_g  = (const float*)d_in[7];
    const float* ln2_b  = (const float*)d_in[8];
    const float* w1     = (const float*)d_in[9];
    const float* b1     = (const float*)d_in[10];
    const float* w2     = (const float*)d_in[11];
    const float* b2     = (const float*)d_in[12];

    char* ws = (char*)d_ws;
    // region map (bytes):
    //   [0, 25165824)           ln1 bf16   -- later reused as low part of mid
    //   [25165824, 100663296)   qkv bf16   -- later reused as high part of mid
    //   [0, 100663296)          mid bf16 [32768,1536]
    //   [100663296, 125829120)  attn bf16
    //   [125829120, 176160768)  y f32 (residual) -- later reused as hbuf f32
    //   [176160768, 201326592)  ln2 bf16
    unsigned short* ln1  = (unsigned short*)(ws + 0);
    unsigned short* qkv  = (unsigned short*)(ws + 25165824);
    unsigned short* mid  = (unsigned short*)(ws + 0);
    unsigned short* attn = (unsigned short*)(ws + 100663296);
    float*          y    = (float*)(ws + 125829120);
    unsigned short* ln2  = (unsigned short*)(ws + 176160768);
    float*          hbuf = y;

    k_ln1<<<NWIN, 64, 0, stream>>>(x, ln1_g, ln1_b, ln1);
    k_gemm<0><<<dim3(18, 512), 256, 0, stream>>>(ln1, qkv_w, qkv_b, qkv, nullptr, 1152, 384);
    k_attn<<<NWIN * HEADS, 64, 0, stream>>>(qkv, attn);
    k_gemm<2><<<dim3(6, 512), 256, 0, stream>>>(attn, proj_w, proj_b, y, x, 384, 384);
    k_ln2<<<NTOK, 64, 0, stream>>>(y, ln2_g, ln2_b, ln2);
    k_gemm<1><<<dim3(24, 512), 256, 0, stream>>>(ln2, w1, b1, mid, nullptr, 1536, 384);
    k_gemm<3><<<dim3(6, 512), 256, 0, stream>>>(mid, w2, b2, hbuf, nullptr, 384, 1536);
    k_out<<<NWIN, 256, 0, stream>>>(hbuf, (float*)d_out);
}

// Round 2
// 687.680 us; speedup vs baseline: 2.5310x; 2.5310x over previous
//
#include <hip/hip_runtime.h>
#include <hip/hip_bf16.h>
#include <math.h>

#define DIM   384
#define HEADS 8
#define HD    48
#define NTOK  32768   // 8 * 64 * 64
#define NWIN  512     // 8 images * 64 windows

typedef __attribute__((ext_vector_type(8))) short bf16x8;
typedef __attribute__((ext_vector_type(4))) float f32x4;

__device__ __forceinline__ float bf2f(unsigned short u) {
    unsigned int v = ((unsigned int)u) << 16;
    return __uint_as_float(v);
}
__device__ __forceinline__ unsigned short f2bf(float f) {
    unsigned int x = __float_as_uint(f);
    unsigned int r = (x + 0x7fffu + ((x >> 16) & 1u)) >> 16;  // RNE
    return (unsigned short)r;
}

// token (window order) -> source pixel of x (accounting for roll by -SHIFT)
__device__ __forceinline__ void tok2src(int tok, int& b, int& hs, int& ws) {
    int bb  = tok >> 12;          // 4096 tokens per image
    int win = (tok >> 6) & 63;
    int t   = tok & 63;
    int hi = win >> 3, wi = win & 7;
    int r  = t >> 3,  cc = t & 7;
    b  = bb;
    hs = (hi * 8 + r  + 4) & 63;
    ws = (wi * 8 + cc + 4) & 63;
}

// ------------- weight convert: W f32 [K][N] -> Wt bf16 [N][K] --------------
__global__ __launch_bounds__(256) void k_wt(const float* __restrict__ W,
                                            unsigned short* __restrict__ Wt,
                                            int K, int N) {
    int idx = blockIdx.x * 256 + threadIdx.x;
    if (idx >= K * N) return;
    int n = idx / K, k = idx - n * K;
    Wt[idx] = f2bf(W[(size_t)k * N + n]);
}

// ---------------- Kernel 1: gather + LayerNorm1 -> ln1 (bf16, token order) ---
__global__ __launch_bounds__(64) void k_ln1(const float* __restrict__ x,
                                            const float* __restrict__ g,
                                            const float* __restrict__ bt,
                                            unsigned short* __restrict__ ln1) {
    int win = blockIdx.x;
    int t   = threadIdx.x;
    int b  = win >> 6;
    int hi = (win >> 3) & 7;
    int wi = win & 7;
    int r = t >> 3, cc = t & 7;
    int hs = (hi * 8 + r + 4) & 63;
    int wsrc = (wi * 8 + cc + 4) & 63;
    const float* px = x + (size_t)b * DIM * 4096 + hs * 64 + wsrc;

    float sum = 0.f, sq = 0.f;
    for (int c = 0; c < DIM; c++) {
        float v = px[(size_t)c * 4096];
        sum += v; sq += v * v;
    }
    float mean = sum * (1.0f / DIM);
    float var  = sq * (1.0f / DIM) - mean * mean;
    float rstd = rsqrtf(var + 1e-5f);

    __shared__ unsigned short tile[64][DIM + 2];
    for (int c = 0; c < DIM; c++) {
        float v = (px[(size_t)c * 4096] - mean) * rstd * g[c] + bt[c];
        tile[t][c] = f2bf(v);
    }
    __syncthreads();
    int tok0 = win * 64;
    for (int tk = 0; tk < 64; tk++) {
        #pragma unroll
        for (int i = 0; i < 6; i++) {
            int c = i * 64 + t;
            ln1[(size_t)(tok0 + tk) * DIM + c] = tile[tk][c];
        }
    }
}

// ---------------- MFMA GEMM: C[M,N] = A[M,K](bf16) * Bt[N,K]^T(bf16) + bias
// 128x128 tile, 4 waves (2x2), 4x4 grid of 16x16x32 MFMA per wave, BK=32.
// LDS layout (fragment order): [kgroup(4)][row(128)][8 bf16]
// EPI: 0 = bias -> bf16; 1 = bias+gelu -> bf16; 2 = bias+residual gather -> f32;
//      3 = bias -> f32
template <int EPI>
__global__ __launch_bounds__(256) void k_gemm_mfma(
        const unsigned short* __restrict__ A,
        const unsigned short* __restrict__ Bt,
        const float* __restrict__ bias,
        void* __restrict__ Cout,
        const float* __restrict__ xres,
        int N, int K) {
    __shared__ __align__(16) unsigned short Alds[4 * 128 * 8];
    __shared__ __align__(16) unsigned short Blds[4 * 128 * 8];
    int tid  = threadIdx.x;
    int lane = tid & 63;
    int wave = tid >> 6;
    int wm = wave >> 1, wn = wave & 1;
    int quad = lane >> 4, l15 = lane & 15;
    int m0 = blockIdx.y * 128, n0 = blockIdx.x * 128;

    f32x4 acc[4][4] = {};

    for (int k0 = 0; k0 < K; k0 += 32) {
        // stage A,B tiles: each wave issues 2 A-chunks + 2 B-chunks of 1 KB
        #pragma unroll
        for (int i = 0; i < 2; i++) {
            int c = wave + i * 4;      // 0..7
            int g = c & 3, j = c >> 2; // kgroup, row-half
            const unsigned short* gpA = A + (size_t)(m0 + j * 64 + lane) * K + k0 + g * 8;
            __builtin_amdgcn_global_load_lds(
                (const __attribute__((address_space(1))) void*)gpA,
                (__attribute__((address_space(3))) void*)&Alds[(g * 128 + j * 64) * 8],
                16, 0, 0);
            const unsigned short* gpB = Bt + (size_t)(n0 + j * 64 + lane) * K + k0 + g * 8;
            __builtin_amdgcn_global_load_lds(
                (const __attribute__((address_space(1))) void*)gpB,
                (__attribute__((address_space(3))) void*)&Blds[(g * 128 + j * 64) * 8],
                16, 0, 0);
        }
        __syncthreads();

        bf16x8 af[4], bfr[4];
        #pragma unroll
        for (int r = 0; r < 4; r++)
            af[r] = *(const bf16x8*)&Alds[(quad * 128 + wm * 64 + r * 16 + l15) * 8];
        #pragma unroll
        for (int r2 = 0; r2 < 4; r2++)
            bfr[r2] = *(const bf16x8*)&Blds[(quad * 128 + wn * 64 + r2 * 16 + l15) * 8];
        #pragma unroll
        for (int r = 0; r < 4; r++)
            #pragma unroll
            for (int r2 = 0; r2 < 4; r2++)
                acc[r][r2] = __builtin_amdgcn_mfma_f32_16x16x32_bf16(
                                 af[r], bfr[r2], acc[r][r2], 0, 0, 0);
        __syncthreads();
    }

    // epilogue: D[row][col] row=(quad*4+reg), col=l15 within each 16x16 tile
    #pragma unroll
    for (int r2 = 0; r2 < 4; r2++) {
        int n = n0 + wn * 64 + r2 * 16 + l15;
        float bn = bias[n];
        #pragma unroll
        for (int r = 0; r < 4; r++) {
            #pragma unroll
            for (int reg = 0; reg < 4; reg++) {
                int m = m0 + wm * 64 + r * 16 + quad * 4 + reg;
                float v = acc[r][r2][reg] + bn;
                if (EPI == 0) {
                    ((unsigned short*)Cout)[(size_t)m * N + n] = f2bf(v);
                } else if (EPI == 1) {
                    v = 0.5f * v * (1.0f + erff(v * 0.70710678118654752f));
                    ((unsigned short*)Cout)[(size_t)m * N + n] = f2bf(v);
                } else if (EPI == 2) {
                    int b, hs, ws_;
                    tok2src(m, b, hs, ws_);
                    v += xres[(((size_t)b * DIM + n) * 64 + hs) * 64 + ws_];
                    ((float*)Cout)[(size_t)m * N + n] = v;
                } else {
                    ((float*)Cout)[(size_t)m * N + n] = v;
                }
            }
        }
    }
}

// ---------------- attention per (window, head) ------------------
__global__ __launch_bounds__(64) void k_attn(const unsigned short* __restrict__ qkv,
                                             unsigned short* __restrict__ attn) {
    int win  = blockIdx.x >> 3;
    int head = blockIdx.x & 7;
    int t    = threadIdx.x;
    int tok0 = win * 64;

    __shared__ float Ks[64][52];
    __shared__ float Vs[64][52];

    const unsigned short* rowp = qkv + (size_t)(tok0 + t) * (3 * DIM);
    #pragma unroll
    for (int d = 0; d < HD; d++) {
        Ks[t][d] = bf2f(rowp[DIM + head * HD + d]);
        Vs[t][d] = bf2f(rowp[2 * DIM + head * HD + d]);
    }
    const float scale = 0.14433756729740643f;  // 48^-0.5
    float q[HD];
    #pragma unroll
    for (int d = 0; d < HD; d++) q[d] = bf2f(rowp[head * HD + d]) * scale;
    __syncthreads();

    float s[64];
    float mx = -1e30f;
    #pragma unroll
    for (int m = 0; m < 64; m++) {
        float acc = 0.f;
        #pragma unroll
        for (int d4 = 0; d4 < HD / 4; d4++) {
            float4 kk = *(const float4*)&Ks[m][d4 * 4];
            acc += q[d4 * 4 + 0] * kk.x + q[d4 * 4 + 1] * kk.y
                 + q[d4 * 4 + 2] * kk.z + q[d4 * 4 + 3] * kk.w;
        }
        s[m] = acc;
        mx = fmaxf(mx, acc);
    }
    float denom = 0.f;
    #pragma unroll
    for (int m = 0; m < 64; m++) {
        float e = __expf(s[m] - mx);
        s[m] = e;
        denom += e;
    }
    float inv = 1.0f / denom;
    float out[HD];
    #pragma unroll
    for (int d = 0; d < HD; d++) out[d] = 0.f;
    #pragma unroll
    for (int m = 0; m < 64; m++) {
        float p = s[m] * inv;
        #pragma unroll
        for (int d4 = 0; d4 < HD / 4; d4++) {
            float4 vv = *(const float4*)&Vs[m][d4 * 4];
            out[d4 * 4 + 0] += p * vv.x;
            out[d4 * 4 + 1] += p * vv.y;
            out[d4 * 4 + 2] += p * vv.z;
            out[d4 * 4 + 3] += p * vv.w;
        }
    }
    unsigned short* op = attn + (size_t)(tok0 + t) * DIM + head * HD;
    #pragma unroll
    for (int d = 0; d < HD; d++) op[d] = f2bf(out[d]);
}

// ---------------- LayerNorm2 over y (f32) -> ln2 (bf16) ----------
__global__ __launch_bounds__(64) void k_ln2(const float* __restrict__ y,
                                            const float* __restrict__ g,
                                            const float* __restrict__ bt,
                                            unsigned short* __restrict__ out) {
    int tok = blockIdx.x;
    int t   = threadIdx.x;
    const float* row = y + (size_t)tok * DIM;
    float v[6];
    float sum = 0.f, sq = 0.f;
    #pragma unroll
    for (int i = 0; i < 6; i++) {
        v[i] = row[i * 64 + t];
        sum += v[i]; sq += v[i] * v[i];
    }
    #pragma unroll
    for (int o = 32; o > 0; o >>= 1) {
        sum += __shfl_xor(sum, o, 64);
        sq  += __shfl_xor(sq, o, 64);
    }
    float mean = sum * (1.0f / DIM);
    float var  = sq * (1.0f / DIM) - mean * mean;
    float rstd = rsqrtf(var + 1e-5f);
    unsigned short* orow = out + (size_t)tok * DIM;
    #pragma unroll
    for (int i = 0; i < 6; i++) {
        int c = i * 64 + t;
        orow[c] = f2bf((v[i] - mean) * rstd * g[c] + bt[c]);
    }
}

// ---------------- un-permute + transpose to [B,C,H,W] ------------
__global__ __launch_bounds__(256) void k_out(const float* __restrict__ hbuf,
                                             float* __restrict__ out) {
    int bh = blockIdx.x;
    int b = bh >> 6, h = bh & 63;
    int t = threadIdx.x;
    __shared__ float T[64][193];
    int hh = (h + 60) & 63;
    int hi = hh >> 3, r = hh & 7;
    for (int half = 0; half < 2; half++) {
        int c0 = half * 192;
        for (int idx = t; idx < 64 * 192; idx += 256) {
            int w = idx / 192;
            int c = idx - w * 192;
            int ww = (w + 60) & 63;
            int wi = ww >> 3, cc2 = ww & 7;
            int tok = ((b * 8 + hi) * 8 + wi) * 64 + r * 8 + cc2;
            T[w][c] = hbuf[(size_t)tok * DIM + c0 + c];
        }
        __syncthreads();
        for (int idx = t; idx < 64 * 192; idx += 256) {
            int cc = idx >> 6;
            int w  = idx & 63;
            out[(((size_t)b * DIM + c0 + cc) * 64 + h) * 64 + w] = T[w][cc];
        }
        __syncthreads();
    }
}

extern "C" void kernel_launch(void* const* d_in, const int* in_sizes, int n_in,
                              void* d_out, int out_size, void* d_ws, size_t ws_size,
                              hipStream_t stream) {
    const float* x      = (const float*)d_in[0];
    const float* qkv_w  = (const float*)d_in[1];
    const float* qkv_b  = (const float*)d_in[2];
    const float* proj_w = (const float*)d_in[3];
    const float* proj_b = (const float*)d_in[4];
    const float* ln1_g  = (const float*)d_in[5];
    const float* ln1_b  = (const float*)d_in[6];
    const float* ln2_g  = (const float*)d_in[7];
    const float* ln2_b  = (const float*)d_in[8];
    const float* w1     = (const float*)d_in[9];
    const float* b1     = (const float*)d_in[10];
    const float* w2     = (const float*)d_in[11];
    const float* b2     = (const float*)d_in[12];

    char* ws = (char*)d_ws;
    // region map (bytes), peak 180,355,072 <= proven ws capacity 201,326,592:
    //   [0,        884736)     qkv_wt bf16 [1152][384]
    //   [884736,   1179648)    proj_wt bf16 [384][384]
    //   [1179648,  2359296)    w1t bf16 [1536][384]
    //   [2359296,  3538944)    w2t bf16 [384][1536]
    //   [4194304,  29360128)   ln1 bf16 [32768][384]   -- reused later as ln2
    //   [29360128, 104857600)  qkv bf16 [32768][1152]  -- reused later as mid(lo)
    //   [104857600,130023424)  attn bf16 [32768][384]  -- reused later as mid(hi)
    //   [130023424,180355072)  y f32 [32768][384]      -- reused as hbuf
    unsigned short* qkv_wt  = (unsigned short*)(ws + 0);
    unsigned short* proj_wt = (unsigned short*)(ws + 884736);
    unsigned short* w1t     = (unsigned short*)(ws + 1179648);
    unsigned short* w2t     = (unsigned short*)(ws + 2359296);
    unsigned short* ln1     = (unsigned short*)(ws + 4194304);
    unsigned short* qkv     = (unsigned short*)(ws + 29360128);
    unsigned short* attn    = (unsigned short*)(ws + 104857600);
    float*          y       = (float*)(ws + 130023424);
    unsigned short* ln2     = ln1;
    unsigned short* mid     = qkv;      // [32768][1536] bf16 = 100663296 B
    float*          hbuf    = y;

    // weight converts (f32 [K][N] -> bf16 [N][K])
    k_wt<<<(384 * 1152 + 255) / 256, 256, 0, stream>>>(qkv_w, qkv_wt, 384, 1152);
    k_wt<<<(384 * 384 + 255) / 256, 256, 0, stream>>>(proj_w, proj_wt, 384, 384);
    k_wt<<<(384 * 1536 + 255) / 256, 256, 0, stream>>>(w1, w1t, 384, 1536);
    k_wt<<<(1536 * 384 + 255) / 256, 256, 0, stream>>>(w2, w2t, 1536, 384);

    k_ln1<<<NWIN, 64, 0, stream>>>(x, ln1_g, ln1_b, ln1);
    k_gemm_mfma<0><<<dim3(9, 256), 256, 0, stream>>>(ln1, qkv_wt, qkv_b, qkv, nullptr, 1152, 384);
    k_attn<<<NWIN * HEADS, 64, 0, stream>>>(qkv, attn);
    k_gemm_mfma<2><<<dim3(3, 256), 256, 0, stream>>>(attn, proj_wt, proj_b, y, x, 384, 384);
    k_ln2<<<NTOK, 64, 0, stream>>>(y, ln2_g, ln2_b, ln2);
    k_gemm_mfma<1><<<dim3(12, 256), 256, 0, stream>>>(ln2, w1t, b1, mid, nullptr, 1536, 384);
    k_gemm_mfma<3><<<dim3(3, 256), 256, 0, stream>>>(mid, w2t, b2, hbuf, nullptr, 384, 1536);
    k_out<<<NWIN, 256, 0, stream>>>(hbuf, (float*)d_out);
}